// Round 14
// baseline (169.709 us; speedup 1.0000x reference)
//
#include <hip/hip_runtime.h>
#include <math.h>

// Shapes: B=3200, L=7, H=8, E=64, S=56, D=64, N=50
// queries [B,7,8,64], keys [B,56,8,64], values [B,56,8,64], mask [50,7,56]
// out [B,7,8,64] fp32.
//
// R11 (best, 160.6 us) + 2 UNITS PER WORKGROUP. Profiled WG throughput was
// ~115 WG/us across six structurally different single-wave-WG kernels
// (R1/R3/R4/R6/R11/R13) -> hard dispatch-rate ceiling; bench mode shows the
// same signature (~158 WG/us for both R11 and R13). Also: FETCH_SIZE
// under-reports ~2x on gfx950 (unique inputs are 780 MB; counter says 381),
// so R11 is really at ~5.1 TB/s = 81% of achievable - the residual gap IS
// the dispatch cap. This kernel packs 2 independent waves (2 units) per
// 128-thread WG -> 12800 WGs, halving the dispatch floor, with R11's
// per-unit flow untouched: K DMA (chunk-XOR pre-swizzled src) -> Q(7) ->
// mask(7) -> V DMA (linear); counted vmcnt(28) so mask+V fly through
// scores; vmcnt(0) before PV. Scores lane=s (K fp32 b128 XOR-balanced x
// Q fp16 uniform bcast), shuffle softmax (no max-sub, scores bounded),
// P fp32 overlays dead K, PV lane=d (V b32 2-way free x P uniform b128),
// deferred normalization. LDS 59.1 KB -> 2 blocks/CU = 4 waves/CU (same
// residency as R11). No barriers, no inter-wave coupling.

typedef __attribute__((ext_vector_type(8))) _Float16 half8;

#define GLDS(gp, lp) __builtin_amdgcn_global_load_lds(                        \
    (const __attribute__((address_space(1))) void*)(gp),                      \
    (__attribute__((address_space(3))) void*)(lp), 16, 0, 0)

__launch_bounds__(128, 4)
__global__ void fullattn_kernel(const float* __restrict__ q,
                                const float* __restrict__ k,
                                const float* __restrict__ v,
                                const float* __restrict__ mask,
                                float* __restrict__ out,
                                int nstations) {
    __shared__ __align__(16) float    KL2[2][56 * 64];  // 28672 B; P overlays
    __shared__ __align__(16) float    VL2[2][56 * 64];  // 28672 B
    __shared__ __align__(16) _Float16 QL2[2][7 * 64];   // 1792 B

    const int lane = threadIdx.x & 63;
    const int wid  = __builtin_amdgcn_readfirstlane(threadIdx.x >> 6);
    float*    KL = KL2[wid];
    float*    VL = VL2[wid];
    _Float16* QL = QL2[wid];

    const int unit = blockIdx.x * 2 + wid;
    const int b    = unit >> 3;
    const int h    = unit & 7;
    const int st   = b % nstations;

    const int kbase = b * 28672 + h * 64;  // keys/values
    const int qbase = b * 3584  + h * 64;  // queries/out

    const int rr = lane >> 4;   // DMA row-within-group
    const int pp = lane & 15;   // DMA slot

    // ---- issue group 1: K DMA, fp32, chunk-XOR pre-swizzled source ----
    // DMA j writes LDS floats [j*256,(j+1)*256): row = 4j+rr, slot pp holds
    // logical chunk c = pp ^ (row&15) so score reads at slot (c ^ (s&15))
    // are bank-balanced.
#pragma unroll
    for (int j = 0; j < 14; ++j) {
        const int row = j * 4 + rr;
        const int c   = pp ^ (row & 15);
        GLDS(k + kbase + row * 512 + c * 4, (char*)KL + j * 1024);
    }
    __builtin_amdgcn_sched_barrier(0);

    // ---- issue group 2: Q (7 dwords, e = lane) ----
    float qr[7];
#pragma unroll
    for (int l = 0; l < 7; ++l) qr[l] = q[qbase + l * 512 + lane];
    __builtin_amdgcn_sched_barrier(0);

    // ---- issue group 3: mask (7 dwords, pre-scaled) ----
    const int ml = (lane < 56) ? lane : 55;  // clamped s index
    float m[7];
#pragma unroll
    for (int l = 0; l < 7; ++l)
        m[l] = mask[st * 392 + l * 56 + ml] * 0.125f;  // scale = 1/sqrt(64)
    __builtin_amdgcn_sched_barrier(0);

    // ---- issue group 4: V DMA, linear layout ----
#pragma unroll
    for (int j = 0; j < 14; ++j) {
        const int row = j * 4 + rr;
        GLDS(v + kbase + row * 512 + pp * 4, (char*)VL + j * 1024);
    }
    __builtin_amdgcn_sched_barrier(0);

    // ---- fence: K done (28 newer = Q7 + mask7 + V14 stay in flight) ----
    asm volatile("s_waitcnt vmcnt(28)" ::: "memory");
    __builtin_amdgcn_sched_barrier(0);

    // ---- Q -> LDS fp16 (compiler auto-waits qr) ----
#pragma unroll
    for (int l = 0; l < 7; ++l) QL[l * 64 + lane] = (_Float16)qr[l];

    // ---- scores: lane = s, K fp32 b128 (XOR slots) x Q fp16 uniform ----
    const int x16 = ml & 15;
    float acc[7];
#pragma unroll
    for (int l = 0; l < 7; ++l) acc[l] = 0.0f;

#pragma unroll
    for (int c2 = 0; c2 < 8; ++c2) {
        const float4 kv0 = *(const float4*)(&KL[ml * 64 + (((2 * c2)     ^ x16) << 2)]);
        const float4 kv1 = *(const float4*)(&KL[ml * 64 + (((2 * c2 + 1) ^ x16) << 2)]);
#pragma unroll
        for (int l = 0; l < 7; ++l) {
            const half8 qv = *(const half8*)(&QL[l * 64 + c2 * 8]);  // uniform bcast
            acc[l] = fmaf(kv0.x, (float)qv[0], acc[l]);
            acc[l] = fmaf(kv0.y, (float)qv[1], acc[l]);
            acc[l] = fmaf(kv0.z, (float)qv[2], acc[l]);
            acc[l] = fmaf(kv0.w, (float)qv[3], acc[l]);
            acc[l] = fmaf(kv1.x, (float)qv[4], acc[l]);
            acc[l] = fmaf(kv1.y, (float)qv[5], acc[l]);
            acc[l] = fmaf(kv1.z, (float)qv[6], acc[l]);
            acc[l] = fmaf(kv1.w, (float)qv[7], acc[l]);
        }
    }

    // ---- softmax (no max-subtraction; scores bounded); P overlays K ----
    float* pbuf = KL;
    float rdenom[7];
#pragma unroll
    for (int l = 0; l < 7; ++l) {
        const float sc = acc[l] * m[l];
        const float p  = (lane < 56) ? __expf(sc) : 0.0f;
        float sum = p;
#pragma unroll
        for (int off = 32; off >= 1; off >>= 1)
            sum += __shfl_xor(sum, off);
        pbuf[l * 64 + lane] = p;
        rdenom[l] = __builtin_amdgcn_rcpf(sum);
    }

    // ---- fence: V done ----
    asm volatile("s_waitcnt vmcnt(0)" ::: "memory");
    __builtin_amdgcn_sched_barrier(0);

    // ---- PV: lane = d; V b32 from LDS (2-way, free) x P uniform b128 ----
    float facc[7];
#pragma unroll
    for (int l = 0; l < 7; ++l) facc[l] = 0.0f;

#pragma unroll
    for (int s4 = 0; s4 < 14; ++s4) {
        const float vv0 = VL[(s4 * 4 + 0) * 64 + lane];
        const float vv1 = VL[(s4 * 4 + 1) * 64 + lane];
        const float vv2 = VL[(s4 * 4 + 2) * 64 + lane];
        const float vv3 = VL[(s4 * 4 + 3) * 64 + lane];
#pragma unroll
        for (int l = 0; l < 7; ++l) {
            const float4 p4 = *(const float4*)(&pbuf[l * 64 + s4 * 4]);  // uniform bcast
            facc[l] = fmaf(p4.x, vv0, facc[l]);
            facc[l] = fmaf(p4.y, vv1, facc[l]);
            facc[l] = fmaf(p4.z, vv2, facc[l]);
            facc[l] = fmaf(p4.w, vv3, facc[l]);
        }
    }

    // ---- epilogue: deferred normalization + coalesced store ----
#pragma unroll
    for (int l = 0; l < 7; ++l)
        out[qbase + l * 512 + lane] = facc[l] * rdenom[l];
}

extern "C" void kernel_launch(void* const* d_in, const int* in_sizes, int n_in,
                              void* d_out, int out_size, void* d_ws, size_t ws_size,
                              hipStream_t stream) {
    const float* q    = (const float*)d_in[0];
    const float* k    = (const float*)d_in[1];
    const float* v    = (const float*)d_in[2];
    const float* mask = (const float*)d_in[3];
    float* out        = (float*)d_out;

    const int B = in_sizes[0] / (7 * 8 * 64);        // 3200
    const int nstations = in_sizes[3] / (7 * 56);    // 50
    const int nunits = B * 8;                        // 25600

    fullattn_kernel<<<dim3(nunits / 2), dim3(128), 0, stream>>>(q, k, v, mask, out, nstations);
}

// Round 15
// 166.250 us; speedup vs baseline: 1.0208x; 1.0208x over previous
//
#include <hip/hip_runtime.h>
#include <math.h>

// Shapes: B=3200, L=7, H=8, E=64, S=56, D=64, N=50
// queries [B,7,8,64], keys [B,56,8,64], values [B,56,8,64], mask [50,7,56]
// out [B,7,8,64] fp32.
//
// R11 (160.6 us) MINUS THE V LDS BUFFER. R14 falsified the dispatch-rate
// theory (half the WGs, same time). Real bytes are 826 MB (FETCH_SIZE
// under-reports ~2x; WRITE_SIZE is exact) -> R11 ran at 5.14 TB/s = 82% of
// the 6.3 TB/s ceiling. The residual gap: 29.7 KB LDS/unit -> 4 waves/CU =
// 1 wave/SIMD, so each wave's serial compute/wait segments (VALUBusy 22%)
// are unhidden. V needs no staging (each row consumed once, in order):
// stream it into a 3-buffer rolling register window (24 VGPRs, 24-row
// lookahead). LDS drops to 15.2 KB -> 8-10 blocks/CU = 2-2.5 waves/SIMD,
// combining R1-level residency with R11-level batched issue (K via
// global_load_lds with chunk-XOR pre-swizzled source + counted vmcnt,
// never a drain). Scores lane=s (K fp32 b128 XOR-balanced x Q fp16
// uniform bcast from QL), shuffle softmax (no max-sub, scores bounded),
// P fp32 overlays dead K, PV lane=d consumes the rolling V window x P
// uniform b128, deferred normalization. launch_bounds(64,2) keeps the
// 256-VGPR budget so the window stays in registers (watch WRITE_SIZE for
// spill: must stay 44800).

typedef __attribute__((ext_vector_type(8))) _Float16 half8;

#define GLDS(gp, lp) __builtin_amdgcn_global_load_lds(                        \
    (const __attribute__((address_space(1))) void*)(gp),                      \
    (__attribute__((address_space(3))) void*)(lp), 16, 0, 0)

__launch_bounds__(64, 2)
__global__ void fullattn_kernel(const float* __restrict__ q,
                                const float* __restrict__ k,
                                const float* __restrict__ v,
                                const float* __restrict__ mask,
                                float* __restrict__ out,
                                int nstations) {
    __shared__ __align__(16) float    KL[56 * 64];  // 14336 B; P overlays after scores
    __shared__ __align__(16) _Float16 QL[7 * 64];   // 896 B   (total 15232 B)

    const int lane = threadIdx.x;     // 0..63
    const int unit = blockIdx.x;
    const int b    = unit >> 3;
    const int h    = unit & 7;
    const int st   = b % nstations;

    const int kbase = b * 28672 + h * 64;  // keys/values
    const int qbase = b * 3584  + h * 64;  // queries/out

    const int rr = lane >> 4;   // DMA row-within-group
    const int pp = lane & 15;   // DMA slot

    // ---- group 1: K DMA, fp32, chunk-XOR pre-swizzled source ----
    // DMA j fills LDS floats [j*256,(j+1)*256): row = 4j+rr; slot pp holds
    // logical chunk c = pp ^ (row&15) so score reads at (c ^ (s&15)) are
    // bank-balanced.
#pragma unroll
    for (int j = 0; j < 14; ++j) {
        const int row = j * 4 + rr;
        const int c   = pp ^ (row & 15);
        GLDS(k + kbase + row * 512 + c * 4, (char*)KL + j * 1024);
    }
    __builtin_amdgcn_sched_barrier(0);

    // ---- group 2: Q (7 dwords, e = lane) ----
    float qr[7];
#pragma unroll
    for (int l = 0; l < 7; ++l) qr[l] = q[qbase + l * 512 + lane];
    __builtin_amdgcn_sched_barrier(0);

    // ---- group 3: mask (7 dwords, pre-scaled) ----
    const int ml = (lane < 56) ? lane : 55;  // clamped s index
    float m[7];
#pragma unroll
    for (int l = 0; l < 7; ++l)
        m[l] = mask[st * 392 + l * 56 + ml] * 0.125f;  // scale = 1/sqrt(64)
    __builtin_amdgcn_sched_barrier(0);

    // ---- group 4: V rows 0..7 into register window A ----
    float vA[8], vB[8], vC[8];
#pragma unroll
    for (int i = 0; i < 8; ++i) vA[i] = v[kbase + i * 512 + lane];
    __builtin_amdgcn_sched_barrier(0);

    // ---- fence: K landed (22 newer = Q7 + mask7 + vA8 stay in flight) ----
    asm volatile("s_waitcnt vmcnt(22)" ::: "memory");
    __builtin_amdgcn_sched_barrier(0);

    // ---- Q -> LDS fp16 (compiler auto-waits the qr loads) ----
#pragma unroll
    for (int l = 0; l < 7; ++l) QL[l * 64 + lane] = (_Float16)qr[l];

    // ---- scores: lane = s, K fp32 b128 (XOR slots) x Q fp16 uniform ----
    const int x16 = ml & 15;
    float acc[7];
#pragma unroll
    for (int l = 0; l < 7; ++l) acc[l] = 0.0f;

#pragma unroll
    for (int c2 = 0; c2 < 8; ++c2) {
        const float4 kv0 = *(const float4*)(&KL[ml * 64 + (((2 * c2)     ^ x16) << 2)]);
        const float4 kv1 = *(const float4*)(&KL[ml * 64 + (((2 * c2 + 1) ^ x16) << 2)]);
#pragma unroll
        for (int l = 0; l < 7; ++l) {
            const half8 qv = *(const half8*)(&QL[l * 64 + c2 * 8]);  // uniform bcast
            acc[l] = fmaf(kv0.x, (float)qv[0], acc[l]);
            acc[l] = fmaf(kv0.y, (float)qv[1], acc[l]);
            acc[l] = fmaf(kv0.z, (float)qv[2], acc[l]);
            acc[l] = fmaf(kv0.w, (float)qv[3], acc[l]);
            acc[l] = fmaf(kv1.x, (float)qv[4], acc[l]);
            acc[l] = fmaf(kv1.y, (float)qv[5], acc[l]);
            acc[l] = fmaf(kv1.z, (float)qv[6], acc[l]);
            acc[l] = fmaf(kv1.w, (float)qv[7], acc[l]);
        }
    }

    // ---- V rows 8..23 into windows B,C (land under softmax) ----
#pragma unroll
    for (int i = 0; i < 8; ++i) vB[i] = v[kbase + (8 + i) * 512 + lane];
#pragma unroll
    for (int i = 0; i < 8; ++i) vC[i] = v[kbase + (16 + i) * 512 + lane];

    // ---- softmax (no max-subtraction; scores bounded); P overlays K ----
    float* pbuf = KL;
    float rdenom[7];
#pragma unroll
    for (int l = 0; l < 7; ++l) {
        const float sc = acc[l] * m[l];
        const float p  = (lane < 56) ? __expf(sc) : 0.0f;
        float sum = p;
#pragma unroll
        for (int off = 32; off >= 1; off >>= 1)
            sum += __shfl_xor(sum, off);
        pbuf[l * 64 + lane] = p;
        rdenom[l] = __builtin_amdgcn_rcpf(sum);
    }

    // ---- PV: lane = d; rolling 3-buffer window, 24-row lookahead ----
    float facc[7];
#pragma unroll
    for (int l = 0; l < 7; ++l) facc[l] = 0.0f;

    auto pvg = [&](const float (&vw)[8], int g) {
#pragma unroll
        for (int l = 0; l < 7; ++l) {
            const float4 p0 = *(const float4*)(&pbuf[l * 64 + g * 8]);      // uniform bcast
            const float4 p1 = *(const float4*)(&pbuf[l * 64 + g * 8 + 4]);  // uniform bcast
            facc[l] = fmaf(p0.x, vw[0], facc[l]);
            facc[l] = fmaf(p0.y, vw[1], facc[l]);
            facc[l] = fmaf(p0.z, vw[2], facc[l]);
            facc[l] = fmaf(p0.w, vw[3], facc[l]);
            facc[l] = fmaf(p1.x, vw[4], facc[l]);
            facc[l] = fmaf(p1.y, vw[5], facc[l]);
            facc[l] = fmaf(p1.z, vw[6], facc[l]);
            facc[l] = fmaf(p1.w, vw[7], facc[l]);
        }
    };
    auto ldv = [&](float (&vw)[8], int row0) {
#pragma unroll
        for (int i = 0; i < 8; ++i) vw[i] = v[kbase + (row0 + i) * 512 + lane];
    };

    pvg(vA, 0); ldv(vA, 24);   // consume rows 0-7,  prefetch 24-31
    pvg(vB, 1); ldv(vB, 32);   // consume rows 8-15, prefetch 32-39
    pvg(vC, 2); ldv(vC, 40);   // consume rows 16-23, prefetch 40-47
    pvg(vA, 3); ldv(vA, 48);   // consume rows 24-31, prefetch 48-55
    pvg(vB, 4);                // rows 32-39
    pvg(vC, 5);                // rows 40-47
    pvg(vA, 6);                // rows 48-55

    // ---- epilogue: deferred normalization + coalesced store ----
#pragma unroll
    for (int l = 0; l < 7; ++l)
        out[qbase + l * 512 + lane] = facc[l] * rdenom[l];
}

extern "C" void kernel_launch(void* const* d_in, const int* in_sizes, int n_in,
                              void* d_out, int out_size, void* d_ws, size_t ws_size,
                              hipStream_t stream) {
    const float* q    = (const float*)d_in[0];
    const float* k    = (const float*)d_in[1];
    const float* v    = (const float*)d_in[2];
    const float* mask = (const float*)d_in[3];
    float* out        = (float*)d_out;

    const int B = in_sizes[0] / (7 * 8 * 64);        // 3200
    const int nstations = in_sizes[3] / (7 * 56);    // 50

    fullattn_kernel<<<dim3(B * 8), dim3(64), 0, stream>>>(q, k, v, mask, out, nstations);
}

// Round 16
// 164.093 us; speedup vs baseline: 1.0342x; 1.0131x over previous
//
#include <hip/hip_runtime.h>
#include <math.h>

// Shapes: B=3200, L=7, H=8, E=64, S=56, D=64, N=50
// queries [B,7,8,64], keys [B,56,8,64], values [B,56,8,64], mask [50,7,56]
// out [B,7,8,64] fp32.
//
// R11 (best, 160.6 us) + XCD-AFFINE UNIT MAPPING. R11/R13/R14/R15 (four
// structurally distinct clean kernels) all plateau at 160-170 us = ~5.1
// TB/s real traffic (826 MB) = 81% of the copy ceiling. Remaining lever:
// each K/V logical row is 2 KB = 8 heads x 256 B; with unit=blockIdx the
// hardware round-robin (xcd = blockIdx % 8) scatters one batch's 8 head-
// blocks across all 8 XCDs -> the same 2 KB DRAM row is pulled by 8
// different L2s at uncorrelated times (row-buffer + L2-sector waste).
// Remap: XCD x owns batches [x*400,(x+1)*400): block i -> xcd=i&7,
// j=i>>3, b=xcd*400+(j>>3), h=j&7. Same-batch heads run on ONE XCD at
// adjacent dispatch slots -> each 2 KB row consumed by one L2 in a tight
// window. Everything else is byte-identical to R11: K DMA (chunk-XOR
// pre-swizzled source) -> Q(7) -> mask(7) -> V DMA (linear); counted
// vmcnt(28); scores lane=s (K fp32 b128 XOR-balanced x Q fp16 uniform
// bcast); shuffle softmax (no max-sub, scores bounded); P fp32 overlays
// dead K; vmcnt(0); PV lane=d (V b32 2-way free x P uniform b128);
// deferred normalization.

typedef __attribute__((ext_vector_type(8))) _Float16 half8;

#define GLDS(gp, lp) __builtin_amdgcn_global_load_lds(                        \
    (const __attribute__((address_space(1))) void*)(gp),                      \
    (__attribute__((address_space(3))) void*)(lp), 16, 0, 0)

__launch_bounds__(64, 4)
__global__ void fullattn_kernel(const float* __restrict__ q,
                                const float* __restrict__ k,
                                const float* __restrict__ v,
                                const float* __restrict__ mask,
                                float* __restrict__ out,
                                int nstations, int bpx) {
    __shared__ __align__(16) float    KL[56 * 64];   // 14336 B; P overlays after scores
    __shared__ __align__(16) float    VL[56 * 64];   // 14336 B
    __shared__ __align__(16) _Float16 QL[7 * 64];    // 896 B

    const int lane = threadIdx.x;     // 0..63
    // XCD-affine mapping: xcd = blockIdx % 8 (hardware round-robin), and
    // XCD x owns batches [x*bpx, (x+1)*bpx). Same-batch heads land on the
    // same XCD at adjacent dispatch slots.
    const int i   = blockIdx.x;
    const int xcd = i & 7;
    const int j   = i >> 3;
    const int b   = xcd * bpx + (j >> 3);
    const int h   = j & 7;
    const int st  = b % nstations;

    const int kbase = b * 28672 + h * 64;  // keys/values
    const int qbase = b * 3584  + h * 64;  // queries/out

    const int rr = lane >> 4;   // DMA row-within-group
    const int pp = lane & 15;   // DMA slot

    // ---- issue group 1: K DMA, fp32, chunk-XOR pre-swizzled source ----
    // DMA j writes LDS floats [j*256,(j+1)*256): row = 4j+rr; slot pp holds
    // logical chunk c = pp ^ (row&15) so score reads at slot (c ^ (s&15))
    // are bank-balanced.
#pragma unroll
    for (int jj = 0; jj < 14; ++jj) {
        const int row = jj * 4 + rr;
        const int c   = pp ^ (row & 15);
        GLDS(k + kbase + row * 512 + c * 4, (char*)KL + jj * 1024);
    }
    __builtin_amdgcn_sched_barrier(0);

    // ---- issue group 2: Q (7 dwords, e = lane) ----
    float qr[7];
#pragma unroll
    for (int l = 0; l < 7; ++l) qr[l] = q[qbase + l * 512 + lane];
    __builtin_amdgcn_sched_barrier(0);

    // ---- issue group 3: mask (7 dwords, pre-scaled) ----
    const int ml = (lane < 56) ? lane : 55;  // clamped s index
    float m[7];
#pragma unroll
    for (int l = 0; l < 7; ++l)
        m[l] = mask[st * 392 + l * 56 + ml] * 0.125f;  // scale = 1/sqrt(64)
    __builtin_amdgcn_sched_barrier(0);

    // ---- issue group 4: V DMA, linear layout ----
#pragma unroll
    for (int jj = 0; jj < 14; ++jj) {
        const int row = jj * 4 + rr;
        GLDS(v + kbase + row * 512 + pp * 4, (char*)VL + jj * 1024);
    }
    __builtin_amdgcn_sched_barrier(0);

    // ---- fence: K done (28 newer = Q7 + mask7 + V14 stay in flight) ----
    asm volatile("s_waitcnt vmcnt(28)" ::: "memory");
    __builtin_amdgcn_sched_barrier(0);

    // ---- Q -> LDS fp16 (compiler auto-waits qr) ----
#pragma unroll
    for (int l = 0; l < 7; ++l) QL[l * 64 + lane] = (_Float16)qr[l];

    // ---- scores: lane = s, K fp32 b128 (XOR slots) x Q fp16 uniform ----
    const int x16 = ml & 15;
    float acc[7];
#pragma unroll
    for (int l = 0; l < 7; ++l) acc[l] = 0.0f;

#pragma unroll
    for (int c2 = 0; c2 < 8; ++c2) {
        const float4 kv0 = *(const float4*)(&KL[ml * 64 + (((2 * c2)     ^ x16) << 2)]);
        const float4 kv1 = *(const float4*)(&KL[ml * 64 + (((2 * c2 + 1) ^ x16) << 2)]);
#pragma unroll
        for (int l = 0; l < 7; ++l) {
            const half8 qv = *(const half8*)(&QL[l * 64 + c2 * 8]);  // uniform bcast
            acc[l] = fmaf(kv0.x, (float)qv[0], acc[l]);
            acc[l] = fmaf(kv0.y, (float)qv[1], acc[l]);
            acc[l] = fmaf(kv0.z, (float)qv[2], acc[l]);
            acc[l] = fmaf(kv0.w, (float)qv[3], acc[l]);
            acc[l] = fmaf(kv1.x, (float)qv[4], acc[l]);
            acc[l] = fmaf(kv1.y, (float)qv[5], acc[l]);
            acc[l] = fmaf(kv1.z, (float)qv[6], acc[l]);
            acc[l] = fmaf(kv1.w, (float)qv[7], acc[l]);
        }
    }

    // ---- softmax (no max-subtraction; scores bounded); P overlays K ----
    float* pbuf = KL;
    float rdenom[7];
#pragma unroll
    for (int l = 0; l < 7; ++l) {
        const float sc = acc[l] * m[l];
        const float p  = (lane < 56) ? __expf(sc) : 0.0f;
        float sum = p;
#pragma unroll
        for (int off = 32; off >= 1; off >>= 1)
            sum += __shfl_xor(sum, off);
        pbuf[l * 64 + lane] = p;
        rdenom[l] = __builtin_amdgcn_rcpf(sum);
    }

    // ---- fence: V done ----
    asm volatile("s_waitcnt vmcnt(0)" ::: "memory");
    __builtin_amdgcn_sched_barrier(0);

    // ---- PV: lane = d; V b32 from LDS (2-way, free) x P uniform b128 ----
    float facc[7];
#pragma unroll
    for (int l = 0; l < 7; ++l) facc[l] = 0.0f;

#pragma unroll
    for (int s4 = 0; s4 < 14; ++s4) {
        const float vv0 = VL[(s4 * 4 + 0) * 64 + lane];
        const float vv1 = VL[(s4 * 4 + 1) * 64 + lane];
        const float vv2 = VL[(s4 * 4 + 2) * 64 + lane];
        const float vv3 = VL[(s4 * 4 + 3) * 64 + lane];
#pragma unroll
        for (int l = 0; l < 7; ++l) {
            const float4 p4 = *(const float4*)(&pbuf[l * 64 + s4 * 4]);  // uniform bcast
            facc[l] = fmaf(p4.x, vv0, facc[l]);
            facc[l] = fmaf(p4.y, vv1, facc[l]);
            facc[l] = fmaf(p4.z, vv2, facc[l]);
            facc[l] = fmaf(p4.w, vv3, facc[l]);
        }
    }

    // ---- epilogue: deferred normalization + coalesced store ----
#pragma unroll
    for (int l = 0; l < 7; ++l)
        out[qbase + l * 512 + lane] = facc[l] * rdenom[l];
}

extern "C" void kernel_launch(void* const* d_in, const int* in_sizes, int n_in,
                              void* d_out, int out_size, void* d_ws, size_t ws_size,
                              hipStream_t stream) {
    const float* q    = (const float*)d_in[0];
    const float* k    = (const float*)d_in[1];
    const float* v    = (const float*)d_in[2];
    const float* mask = (const float*)d_in[3];
    float* out        = (float*)d_out;

    const int B = in_sizes[0] / (7 * 8 * 64);        // 3200 (divisible by 8)
    const int nstations = in_sizes[3] / (7 * 56);    // 50
    const int bpx = B / 8;                           // batches per XCD

    fullattn_kernel<<<dim3(B * 8), dim3(64), 0, stream>>>(q, k, v, mask, out,
                                                          nstations, bpx);
}